// Round 6
// baseline (34769.403 us; speedup 1.0000x reference)
//
#include <hip/hip_runtime.h>
#include <stdint.h>
#include <math.h>

#define NVARS 1024
#define KDIM 32
#define BATCH 64
#define NIN 768
#define MAXIT 10

// LDS: Vs float[1024][32] (128 KB) + freeS int[1024] (4 KB) + dvS double[2][32]
#define SMEM_BYTES (131072 + 4096 + 512)

// ---- threefry2x32 block, exactly matching JAX (20 rounds, inject every 4) ----
__device__ __forceinline__ void tf2x32(uint32_t key0, uint32_t key1,
                                       uint32_t& x0, uint32_t& x1) {
  uint32_t ks2 = key0 ^ key1 ^ 0x1BD11BDAu;
  x0 += key0; x1 += key1;
#define TFR(r) { x0 += x1; x1 = (x1 << r) | (x1 >> (32 - r)); x1 ^= x0; }
  TFR(13) TFR(15) TFR(26) TFR(6)
  x0 += key1; x1 += ks2 + 1u;
  TFR(17) TFR(29) TFR(16) TFR(24)
  x0 += ks2;  x1 += key0 + 2u;
  TFR(13) TFR(15) TFR(26) TFR(6)
  x0 += key0; x1 += key1 + 3u;
  TFR(17) TFR(29) TFR(16) TFR(24)
  x0 += key1; x1 += ks2 + 4u;
  TFR(13) TFR(15) TFR(26) TFR(6)
  x0 += ks2;  x1 += key0 + 5u;
#undef TFR
}

// partitionable random_bits (32-bit): counter (0, flat), out = x0 ^ x1
__device__ __forceinline__ uint32_t pbits(uint32_t k0, uint32_t k1, uint32_t flat) {
  uint32_t x0 = 0u, x1 = flat;
  tf2x32(k0, k1, x0, x1);
  return x0 ^ x1;
}

// ---- XLA f32 erf_inv (Giles polynomial) ----
__device__ __forceinline__ float erfinv_xla(float x) {
  float w = -log1pf(-x * x);
  float p;
  if (w < 5.0f) {
    w -= 2.5f;
    p = 2.81022636e-08f;
    p = fmaf(p, w, 3.43273939e-07f);
    p = fmaf(p, w, -3.5233877e-06f);
    p = fmaf(p, w, -4.39150654e-06f);
    p = fmaf(p, w, 0.00021858087f);
    p = fmaf(p, w, -0.00125372503f);
    p = fmaf(p, w, -0.00417768164f);
    p = fmaf(p, w, 0.246640727f);
    p = fmaf(p, w, 1.50140941f);
  } else {
    w = sqrtf(w) - 3.0f;
    p = -0.000200214257f;
    p = fmaf(p, w, 0.000100950558f);
    p = fmaf(p, w, 0.00134934322f);
    p = fmaf(p, w, -0.00367342844f);
    p = fmaf(p, w, 0.00573950773f);
    p = fmaf(p, w, -0.0076224613f);
    p = fmaf(p, w, 0.00943887047f);
    p = fmaf(p, w, 1.00167406f);
    p = fmaf(p, w, 2.83297682f);
  }
  return p * x;
}

__device__ __forceinline__ float bits_to_normal(uint32_t bits) {
  uint32_t fb = (bits >> 9) | 0x3F800000u;
  float f = __uint_as_float(fb) - 1.0f;
  const float lo = -0.99999994f;
  float u = fmaf(f, 2.0f, lo);
  u = fmaxf(lo, u);
  return 1.41421356237f * erfinv_xla(u);
}

// sum across the 32-lane group (lanes sharing tid>>5), f64
__device__ __forceinline__ double red32d(double v) {
  v += __shfl_xor(v, 16);
  v += __shfl_xor(v, 8);
  v += __shfl_xor(v, 4);
  v += __shfl_xor(v, 2);
  v += __shfl_xor(v, 1);
  return v;
}

__global__ void cvtC_kernel(const float* __restrict__ C, double* __restrict__ C64) {
  int i = blockIdx.x * 256 + threadIdx.x;
  C64[i] = (double)C[i];
}

__global__ __launch_bounds__(1024) void mixnet_kernel(
    const double* __restrict__ C64, const float* __restrict__ zin,
    const int* __restrict__ is_in, float* __restrict__ out) {
  extern __shared__ char smemraw[];
  float*  Vs    = (float*)smemraw;                 // [1024][32]
  int*    freeS = (int*)(smemraw + 131072);        // [1024]
  double* dvS   = (double*)(smemraw + 131072 + 4096);  // [2][32]

  const int tid = threadIdx.x;
  const int b   = blockIdx.x;
  const int k   = tid & 31;   // K index
  const int jg  = tid >> 5;   // 0..31; owns rows j == jg (mod 32), reg m = j>>5

  // ---- free flags ----
  {
    int row = tid;
    int fr;
    if (row == 0) fr = 0;
    else if (row <= NIN) fr = (is_in[b * NIN + row - 1] == 0) ? 1 : 0;
    else fr = 1;
    freeS[row] = fr;
  }

  // k1, k2 = jax.random.split(jax.random.key(42))  [partitionable]
  uint32_t a0 = 0u, a1 = 0u; tf2x32(0u, 42u, a0, a1);
  uint32_t b0 = 0u, b1 = 1u; tf2x32(0u, 42u, b0, b1);

  // v0 (f64 normalize)
  double v0kd;
  {
    float raw = bits_to_normal(pbits(a0, a1, (uint32_t)(b * KDIM + k)));
    double n2 = red32d((double)raw * (double)raw);
    v0kd = (double)raw / sqrt(n2);
  }

  const double PI_D = 3.14159265358979323846;

  // Build V (f64 math, f32 storage); thread builds rows n = m*32 + jg
  for (int m = 0; m < 32; ++m) {
    int n = m * 32 + jg;
    double val;
    if (n == 0) {
      val = v0kd;
    } else {
      uint32_t flat = ((uint32_t)(b * NVARS + n)) * KDIM + (uint32_t)k;
      float rf = bits_to_normal(pbits(b0, b1, flat));
      double r   = (double)rf;
      double dot = red32d(r * v0kd);
      double rp  = r - dot * v0kd;
      double rn2 = red32d(rp * rp);
      double rn  = rp / sqrt(rn2);
      val = rn;
      if (n <= NIN) {
        if (is_in[b * NIN + n - 1] > 0) {
          double zf = (double)zin[b * NIN + n - 1];
          val = -cos(PI_D * zf) * v0kd + sin(PI_D * zf) * rn;
        }
      }
    }
    Vs[n * KDIM + k] = (float)val;
  }
  __syncthreads();

  // ---- init G = C64 . V  (registers: Gm[m] = G[32m+jg][k], f64) ----
  double Gm[32];
#pragma unroll
  for (int m = 0; m < 32; ++m) Gm[m] = 0.0;
  {
    const double* cbase = C64 + (size_t)jg * NVARS;  // row jg; row 32m+jg at +m*32768 elems
    for (int j = 0; j < NVARS; j += 2) {
      double vj0 = (double)Vs[j * 32 + k];
      double vj1 = (double)Vs[(j + 1) * 32 + k];
      const double* cj = cbase + j;
#pragma unroll
      for (int m = 0; m < 32; ++m) {
        const double* cp = cj + (size_t)m * 32768;
        Gm[m] = fma(cp[0], vj0, Gm[m]);
        Gm[m] = fma(cp[1], vj1, Gm[m]);
      }
    }
  }
  __syncthreads();

  // ---- solve: 10 sweeps, maintained-G coordinate descent ----
  int rctr = 0;
  for (int it = 0; it < MAXIT; ++it) {
    for (int grp = 0; grp < 32; ++grp) {
      // shadow of this group's register: Ghot = Gm[grp] (uniform select)
      double Ghot = Gm[0];
#pragma unroll
      for (int m = 1; m < 32; ++m) Ghot = (grp == m) ? Gm[m] : Ghot;

      for (int ii = 0; ii < 32; ++ii) {
        const int i = grp * 32 + ii;
        if (freeS[i] == 0) continue;   // uniform per block

        const double* crow  = C64 + (size_t)i * NVARS + jg;  // elems at +32*m
        const double* crow2 = crow + 512;
        // preload first half (issued before barrier; overlaps owner's norm)
        double c0[16];
#pragma unroll
        for (int m2 = 0; m2 < 16; ++m2) c0[m2] = crow[32 * m2];
        double cg = crow[32 * grp];    // coefficient for the shadow row

        const int p = rctr & 1;
        if (jg == ii) {                // owner laneset: rows' update
          double g  = Ghot;
          double s2 = red32d(g * g);
          double gn = fmax(sqrt(s2), 1e-12);
          float  vnf  = (float)(-g / gn);
          float  vold = Vs[i * 32 + k];
          double dv   = (double)vnf - (double)vold;
          Vs[i * 32 + k] = vnf;
          dvS[p * 32 + k] = dv;
        }
        __syncthreads();
        const double dvk = dvS[p * 32 + k];
#pragma unroll
        for (int m2 = 0; m2 < 16; ++m2) Gm[m2] = fma(c0[m2], dvk, Gm[m2]);
#pragma unroll
        for (int m2 = 16; m2 < 32; ++m2)
          Gm[m2] = fma(crow2[32 * (m2 - 16)], dvk, Gm[m2]);
        Ghot = fma(cg, dvk, Ghot);     // keep shadow in sync
        ++rctr;
      }
    }
  }
  __syncthreads();

  // ---- epilogue: z_out = free ? arccos(clip(-V.v0))/pi : z  (f64) ----
  for (int m = 0; m < 32; ++m) {
    int n = m * 32 + jg;
    if (n >= 1 && n <= NIN) {
      float zo;
      if (freeS[n] != 0) {
        double dot = red32d((double)Vs[n * KDIM + k] * v0kd);
        double ca  = fmin(fmax(-dot, -1.0 + 1e-7), 1.0 - 1e-7);
        zo = (float)(acos(ca) / PI_D);
      } else {
        zo = zin[b * NIN + n - 1];
      }
      if (k == 0) out[b * NIN + n - 1] = zo;
    }
  }
}

extern "C" void kernel_launch(void* const* d_in, const int* in_sizes, int n_in,
                              void* d_out, int out_size, void* d_ws, size_t ws_size,
                              hipStream_t stream) {
  const float* C        = (const float*)d_in[0];
  const float* z        = (const float*)d_in[1];
  const int*   is_input = (const int*)d_in[2];
  float*       out      = (float*)d_out;

  double* C64 = (double*)d_ws;  // 8 MB

  (void)hipFuncSetAttribute((const void*)mixnet_kernel,
                            hipFuncAttributeMaxDynamicSharedMemorySize,
                            SMEM_BYTES);

  cvtC_kernel<<<NVARS * NVARS / 256, 256, 0, stream>>>(C, C64);
  mixnet_kernel<<<BATCH, 1024, SMEM_BYTES, stream>>>(C64, z, is_input, out);
}

// Round 7
// 9012.807 us; speedup vs baseline: 3.8578x; 3.8578x over previous
//
#include <hip/hip_runtime.h>
#include <stdint.h>
#include <math.h>

#define NVARS 1024
#define KDIM 32
#define BATCH 64
#define NIN 768
#define MAXIT 10

// LDS: Vs float[1024][32] (128 KB) + freeS int[1024] (4 KB) + dvS float[2][32]
#define SMEM_BYTES (131072 + 4096 + 256)

// ---- threefry2x32 block, exactly matching JAX (20 rounds, inject every 4) ----
__device__ __forceinline__ void tf2x32(uint32_t key0, uint32_t key1,
                                       uint32_t& x0, uint32_t& x1) {
  uint32_t ks2 = key0 ^ key1 ^ 0x1BD11BDAu;
  x0 += key0; x1 += key1;
#define TFR(r) { x0 += x1; x1 = (x1 << r) | (x1 >> (32 - r)); x1 ^= x0; }
  TFR(13) TFR(15) TFR(26) TFR(6)
  x0 += key1; x1 += ks2 + 1u;
  TFR(17) TFR(29) TFR(16) TFR(24)
  x0 += ks2;  x1 += key0 + 2u;
  TFR(13) TFR(15) TFR(26) TFR(6)
  x0 += key0; x1 += key1 + 3u;
  TFR(17) TFR(29) TFR(16) TFR(24)
  x0 += key1; x1 += ks2 + 4u;
  TFR(13) TFR(15) TFR(26) TFR(6)
  x0 += ks2;  x1 += key0 + 5u;
#undef TFR
}

// partitionable random_bits (32-bit): counter (0, flat), out = x0 ^ x1
__device__ __forceinline__ uint32_t pbits(uint32_t k0, uint32_t k1, uint32_t flat) {
  uint32_t x0 = 0u, x1 = flat;
  tf2x32(k0, k1, x0, x1);
  return x0 ^ x1;
}

// ---- XLA f32 erf_inv (Giles polynomial) ----
__device__ __forceinline__ float erfinv_xla(float x) {
  float w = -log1pf(-x * x);
  float p;
  if (w < 5.0f) {
    w -= 2.5f;
    p = 2.81022636e-08f;
    p = fmaf(p, w, 3.43273939e-07f);
    p = fmaf(p, w, -3.5233877e-06f);
    p = fmaf(p, w, -4.39150654e-06f);
    p = fmaf(p, w, 0.00021858087f);
    p = fmaf(p, w, -0.00125372503f);
    p = fmaf(p, w, -0.00417768164f);
    p = fmaf(p, w, 0.246640727f);
    p = fmaf(p, w, 1.50140941f);
  } else {
    w = sqrtf(w) - 3.0f;
    p = -0.000200214257f;
    p = fmaf(p, w, 0.000100950558f);
    p = fmaf(p, w, 0.00134934322f);
    p = fmaf(p, w, -0.00367342844f);
    p = fmaf(p, w, 0.00573950773f);
    p = fmaf(p, w, -0.0076224613f);
    p = fmaf(p, w, 0.00943887047f);
    p = fmaf(p, w, 1.00167406f);
    p = fmaf(p, w, 2.83297682f);
  }
  return p * x;
}

__device__ __forceinline__ float bits_to_normal(uint32_t bits) {
  uint32_t fb = (bits >> 9) | 0x3F800000u;
  float f = __uint_as_float(fb) - 1.0f;
  const float lo = -0.99999994f;
  float u = fmaf(f, 2.0f, lo);
  u = fmaxf(lo, u);
  return 1.41421356237f * erfinv_xla(u);
}

// sum across the 32-lane group (lanes sharing tid>>5)
__device__ __forceinline__ double red32d(double v) {
  v += __shfl_xor(v, 16);
  v += __shfl_xor(v, 8);
  v += __shfl_xor(v, 4);
  v += __shfl_xor(v, 2);
  v += __shfl_xor(v, 1);
  return v;
}
__device__ __forceinline__ float red32f(float v) {
  v += __shfl_xor(v, 16);
  v += __shfl_xor(v, 8);
  v += __shfl_xor(v, 4);
  v += __shfl_xor(v, 2);
  v += __shfl_xor(v, 1);
  return v;
}

__global__ __launch_bounds__(1024, 4) void mixnet_kernel(
    const float* __restrict__ C32, const float* __restrict__ zin,
    const int* __restrict__ is_in, float* __restrict__ out) {
  extern __shared__ char smemraw[];
  float* Vs    = (float*)smemraw;                      // [1024][32]
  int*   freeS = (int*)(smemraw + 131072);             // [1024]
  float* dvS   = (float*)(smemraw + 131072 + 4096);    // [2][32]

  const int tid = threadIdx.x;
  const int b   = blockIdx.x;
  const int k   = tid & 31;   // K index
  const int jg  = tid >> 5;   // 0..31; owns rows j == jg (mod 32), reg m = j>>5

  // ---- free flags ----
  {
    int row = tid;
    int fr;
    if (row == 0) fr = 0;
    else if (row <= NIN) fr = (is_in[b * NIN + row - 1] == 0) ? 1 : 0;
    else fr = 1;
    freeS[row] = fr;
  }

  // k1, k2 = jax.random.split(jax.random.key(42))  [partitionable]
  uint32_t a0 = 0u, a1 = 0u; tf2x32(0u, 42u, a0, a1);
  uint32_t b0 = 0u, b1 = 1u; tf2x32(0u, 42u, b0, b1);

  // v0 (f64 normalize)
  double v0kd;
  {
    float raw = bits_to_normal(pbits(a0, a1, (uint32_t)(b * KDIM + k)));
    double n2 = red32d((double)raw * (double)raw);
    v0kd = (double)raw / sqrt(n2);
  }

  const double PI_D = 3.14159265358979323846;

  // Build V (f64 math, f32 storage); thread builds rows n = m*32 + jg
  for (int m = 0; m < 32; ++m) {
    int n = m * 32 + jg;
    double val;
    if (n == 0) {
      val = v0kd;
    } else {
      uint32_t flat = ((uint32_t)(b * NVARS + n)) * KDIM + (uint32_t)k;
      float rf = bits_to_normal(pbits(b0, b1, flat));
      double r   = (double)rf;
      double dot = red32d(r * v0kd);
      double rp  = r - dot * v0kd;
      double rn2 = red32d(rp * rp);
      double rn  = rp / sqrt(rn2);
      val = rn;
      if (n <= NIN) {
        if (is_in[b * NIN + n - 1] > 0) {
          double zf = (double)zin[b * NIN + n - 1];
          val = -cos(PI_D * zf) * v0kd + sin(PI_D * zf) * rn;
        }
      }
    }
    Vs[n * KDIM + k] = (float)val;
  }
  __syncthreads();

  // ---- init G = C32 . V  (registers: Gm[m] = G[32m+jg][k], f32) ----
  float Gm[32];
#pragma unroll
  for (int m = 0; m < 32; ++m) Gm[m] = 0.f;
  for (int j = 0; j < NVARS; j += 4) {
    float vj0 = Vs[(j)     * 32 + k];
    float vj1 = Vs[(j + 1) * 32 + k];
    float vj2 = Vs[(j + 2) * 32 + k];
    float vj3 = Vs[(j + 3) * 32 + k];
#pragma unroll
    for (int m = 0; m < 32; ++m) {
      const float4 c = *(const float4*)(C32 + (size_t)(m * 32 + jg) * NVARS + j);
      Gm[m] = fmaf(c.x, vj0, Gm[m]);
      Gm[m] = fmaf(c.y, vj1, Gm[m]);
      Gm[m] = fmaf(c.z, vj2, Gm[m]);
      Gm[m] = fmaf(c.w, vj3, Gm[m]);
    }
  }
  __syncthreads();

  // ---- solve: 10 sweeps, maintained-G coordinate descent (f32) ----
  int rctr = 0;
  for (int it = 0; it < MAXIT; ++it) {
    for (int grp = 0; grp < 32; ++grp) {
      // shadow of this group's register: Ghot = Gm[grp] (const-indexed select)
      float Ghot = Gm[0];
#pragma unroll
      for (int m = 1; m < 32; ++m) Ghot = (grp == m) ? Gm[m] : Ghot;

      for (int ii = 0; ii < 32; ++ii) {
        const int i = grp * 32 + ii;
        if (freeS[i] == 0) continue;   // uniform per block; dv==0 exactly -> skip

        const float* crow = C32 + (size_t)i * NVARS + jg;  // elems at +32*m
        // preload all 32 coefficients (lane-uniform broadcast, L2/L3-resident)
        float cpre[32];
#pragma unroll
        for (int m2 = 0; m2 < 32; ++m2) cpre[m2] = crow[32 * m2];
        float cg = crow[32 * grp];     // scalar (avoid dynamic cpre[grp])

        const int p = rctr & 1;
        if (jg == ii) {                // owner laneset: row update
          float g  = Ghot;
          float s2 = red32f(g * g);
          float gn = fmaxf(sqrtf(s2), 1e-12f);
          float vnf  = -g / gn;
          float vold = Vs[i * 32 + k];
          Vs[i * 32 + k] = vnf;
          dvS[p * 32 + k] = vnf - vold;
        }
        __syncthreads();
        const float dvk = dvS[p * 32 + k];
#pragma unroll
        for (int m2 = 0; m2 < 32; ++m2) Gm[m2] = fmaf(cpre[m2], dvk, Gm[m2]);
        Ghot = fmaf(cg, dvk, Ghot);    // keep shadow in sync
        ++rctr;
      }
    }
  }
  __syncthreads();

  // ---- epilogue: z_out = free ? arccos(clip(-V.v0))/pi : z  (f64) ----
  for (int m = 0; m < 32; ++m) {
    int n = m * 32 + jg;
    if (n >= 1 && n <= NIN) {
      float zo;
      if (freeS[n] != 0) {
        double dot = red32d((double)Vs[n * KDIM + k] * v0kd);
        double ca  = fmin(fmax(-dot, -1.0 + 1e-7), 1.0 - 1e-7);
        zo = (float)(acos(ca) / PI_D);
      } else {
        zo = zin[b * NIN + n - 1];
      }
      if (k == 0) out[b * NIN + n - 1] = zo;
    }
  }
}

extern "C" void kernel_launch(void* const* d_in, const int* in_sizes, int n_in,
                              void* d_out, int out_size, void* d_ws, size_t ws_size,
                              hipStream_t stream) {
  const float* C        = (const float*)d_in[0];
  const float* z        = (const float*)d_in[1];
  const int*   is_input = (const int*)d_in[2];
  float*       out      = (float*)d_out;
  (void)d_ws; (void)ws_size;

  (void)hipFuncSetAttribute((const void*)mixnet_kernel,
                            hipFuncAttributeMaxDynamicSharedMemorySize,
                            SMEM_BYTES);

  mixnet_kernel<<<BATCH, 1024, SMEM_BYTES, stream>>>(C, z, is_input, out);
}

// Round 8
// 8337.889 us; speedup vs baseline: 4.1700x; 1.0809x over previous
//
#include <hip/hip_runtime.h>
#include <stdint.h>
#include <math.h>

#define NVARS 1024
#define KDIM 32
#define BATCH 64
#define NIN 768
#define MAXIT 10

// LDS: Vs float[1024][32] (128 KB) + freeS int[1024] (4 KB) + dvS float[2][32]
#define SMEM_BYTES (131072 + 4096 + 256)

// ---- threefry2x32 block, exactly matching JAX (20 rounds, inject every 4) ----
__device__ __forceinline__ void tf2x32(uint32_t key0, uint32_t key1,
                                       uint32_t& x0, uint32_t& x1) {
  uint32_t ks2 = key0 ^ key1 ^ 0x1BD11BDAu;
  x0 += key0; x1 += key1;
#define TFR(r) { x0 += x1; x1 = (x1 << r) | (x1 >> (32 - r)); x1 ^= x0; }
  TFR(13) TFR(15) TFR(26) TFR(6)
  x0 += key1; x1 += ks2 + 1u;
  TFR(17) TFR(29) TFR(16) TFR(24)
  x0 += ks2;  x1 += key0 + 2u;
  TFR(13) TFR(15) TFR(26) TFR(6)
  x0 += key0; x1 += key1 + 3u;
  TFR(17) TFR(29) TFR(16) TFR(24)
  x0 += key1; x1 += ks2 + 4u;
  TFR(13) TFR(15) TFR(26) TFR(6)
  x0 += ks2;  x1 += key0 + 5u;
#undef TFR
}

// partitionable random_bits (32-bit): counter (0, flat), out = x0 ^ x1
__device__ __forceinline__ uint32_t pbits(uint32_t k0, uint32_t k1, uint32_t flat) {
  uint32_t x0 = 0u, x1 = flat;
  tf2x32(k0, k1, x0, x1);
  return x0 ^ x1;
}

// ---- XLA f32 erf_inv (Giles polynomial) ----
__device__ __forceinline__ float erfinv_xla(float x) {
  float w = -log1pf(-x * x);
  float p;
  if (w < 5.0f) {
    w -= 2.5f;
    p = 2.81022636e-08f;
    p = fmaf(p, w, 3.43273939e-07f);
    p = fmaf(p, w, -3.5233877e-06f);
    p = fmaf(p, w, -4.39150654e-06f);
    p = fmaf(p, w, 0.00021858087f);
    p = fmaf(p, w, -0.00125372503f);
    p = fmaf(p, w, -0.00417768164f);
    p = fmaf(p, w, 0.246640727f);
    p = fmaf(p, w, 1.50140941f);
  } else {
    w = sqrtf(w) - 3.0f;
    p = -0.000200214257f;
    p = fmaf(p, w, 0.000100950558f);
    p = fmaf(p, w, 0.00134934322f);
    p = fmaf(p, w, -0.00367342844f);
    p = fmaf(p, w, 0.00573950773f);
    p = fmaf(p, w, -0.0076224613f);
    p = fmaf(p, w, 0.00943887047f);
    p = fmaf(p, w, 1.00167406f);
    p = fmaf(p, w, 2.83297682f);
  }
  return p * x;
}

__device__ __forceinline__ float bits_to_normal(uint32_t bits) {
  uint32_t fb = (bits >> 9) | 0x3F800000u;
  float f = __uint_as_float(fb) - 1.0f;
  const float lo = -0.99999994f;
  float u = fmaf(f, 2.0f, lo);
  u = fmaxf(lo, u);
  return 1.41421356237f * erfinv_xla(u);
}

// sum across the 32-lane group (lanes sharing tid>>5)
__device__ __forceinline__ double red32d(double v) {
  v += __shfl_xor(v, 16);
  v += __shfl_xor(v, 8);
  v += __shfl_xor(v, 4);
  v += __shfl_xor(v, 2);
  v += __shfl_xor(v, 1);
  return v;
}
__device__ __forceinline__ float red32f(float v) {
  v += __shfl_xor(v, 16);
  v += __shfl_xor(v, 8);
  v += __shfl_xor(v, 4);
  v += __shfl_xor(v, 2);
  v += __shfl_xor(v, 1);
  return v;
}

__global__ __launch_bounds__(1024, 4) void mixnet_kernel(
    const float* __restrict__ C32, const float* __restrict__ zin,
    const int* __restrict__ is_in, float* __restrict__ out) {
  extern __shared__ char smemraw[];
  float* Vs    = (float*)smemraw;                      // [1024][32]
  int*   freeS = (int*)(smemraw + 131072);             // [1024]
  float* dvS   = (float*)(smemraw + 131072 + 4096);    // [2][32]

  const int tid = threadIdx.x;
  const int b   = blockIdx.x;
  const int k   = tid & 31;   // K index
  const int jg  = tid >> 5;   // 0..31; owns G rows 32*jg .. 32*jg+31

  // ---- free flags ----
  {
    int row = tid;
    int fr;
    if (row == 0) fr = 0;
    else if (row <= NIN) fr = (is_in[b * NIN + row - 1] == 0) ? 1 : 0;
    else fr = 1;
    freeS[row] = fr;
  }

  // k1, k2 = jax.random.split(jax.random.key(42))  [partitionable]
  uint32_t a0 = 0u, a1 = 0u; tf2x32(0u, 42u, a0, a1);
  uint32_t b0 = 0u, b1 = 1u; tf2x32(0u, 42u, b0, b1);

  // v0 (f64 normalize)
  double v0kd;
  {
    float raw = bits_to_normal(pbits(a0, a1, (uint32_t)(b * KDIM + k)));
    double n2 = red32d((double)raw * (double)raw);
    v0kd = (double)raw / sqrt(n2);
  }

  const double PI_D = 3.14159265358979323846;

  // Build V (f64 math, f32 storage); thread builds rows n = m*32 + jg
  for (int m = 0; m < 32; ++m) {
    int n = m * 32 + jg;
    double val;
    if (n == 0) {
      val = v0kd;
    } else {
      uint32_t flat = ((uint32_t)(b * NVARS + n)) * KDIM + (uint32_t)k;
      float rf = bits_to_normal(pbits(b0, b1, flat));
      double r   = (double)rf;
      double dot = red32d(r * v0kd);
      double rp  = r - dot * v0kd;
      double rn2 = red32d(rp * rp);
      double rn  = rp / sqrt(rn2);
      val = rn;
      if (n <= NIN) {
        if (is_in[b * NIN + n - 1] > 0) {
          double zf = (double)zin[b * NIN + n - 1];
          val = -cos(PI_D * zf) * v0kd + sin(PI_D * zf) * rn;
        }
      }
    }
    Vs[n * KDIM + k] = (float)val;
  }
  __syncthreads();

  // ---- init G: Gm[m] = G[32*jg+m][k] = sum_j C[32jg+m][j] * V[j][k]  (f32) ----
  float Gm[32];
#pragma unroll
  for (int m = 0; m < 32; ++m) Gm[m] = 0.f;
  {
    const float* Cbase = C32 + (size_t)(32 * jg) * NVARS;
    for (int j = 0; j < NVARS; j += 4) {
      float vj0 = Vs[(j)     * 32 + k];
      float vj1 = Vs[(j + 1) * 32 + k];
      float vj2 = Vs[(j + 2) * 32 + k];
      float vj3 = Vs[(j + 3) * 32 + k];
#pragma unroll
      for (int m = 0; m < 32; ++m) {
        const float4 c = *(const float4*)(Cbase + (size_t)m * NVARS + j);
        Gm[m] = fmaf(c.x, vj0, Gm[m]);
        Gm[m] = fmaf(c.y, vj1, Gm[m]);
        Gm[m] = fmaf(c.z, vj2, Gm[m]);
        Gm[m] = fmaf(c.w, vj3, Gm[m]);
      }
    }
  }
  __syncthreads();

  // ---- solve: 10 sweeps, maintained-G coordinate descent (f32) ----
  // Row i: owner laneset jg == (i>>5) holds G[i] in Gm[i&31] (compile-time idx).
  int rctr = 0;
  for (int it = 0; it < MAXIT; ++it) {
    for (int grp = 0; grp < 32; ++grp) {
      const float* Cgrp = C32 + (size_t)(grp * 32) * NVARS + 32 * jg;
#pragma unroll
      for (int ii = 0; ii < 32; ++ii) {
        const int i = grp * 32 + ii;
        if (freeS[i] == 0) continue;   // block-uniform skip (dv would be 0)

        // 8 float4 coefficient loads: C[i][32jg .. 32jg+31] (contiguous).
        // Issued before owner+barrier -> latency self-covered within the row.
        const float* crow = Cgrp + (size_t)ii * NVARS;
        float4 cp[8];
#pragma unroll
        for (int q = 0; q < 8; ++q) cp[q] = *(const float4*)(crow + 4 * q);

        const int p = rctr & 1;
        if (jg == grp) {               // owner laneset: row update
          float g  = Gm[ii];           // compile-time register index
          float s2 = red32f(g * g);
          float gn = fmaxf(sqrtf(s2), 1e-12f);
          float vnf  = -g / gn;
          float vold = Vs[i * 32 + k];
          Vs[i * 32 + k] = vnf;
          dvS[p * 32 + k] = vnf - vold;
        }
        __syncthreads();
        const float dvk = dvS[p * 32 + k];
#pragma unroll
        for (int q = 0; q < 8; ++q) {
          Gm[4 * q]     = fmaf(cp[q].x, dvk, Gm[4 * q]);
          Gm[4 * q + 1] = fmaf(cp[q].y, dvk, Gm[4 * q + 1]);
          Gm[4 * q + 2] = fmaf(cp[q].z, dvk, Gm[4 * q + 2]);
          Gm[4 * q + 3] = fmaf(cp[q].w, dvk, Gm[4 * q + 3]);
        }
        ++rctr;
      }
    }
  }
  __syncthreads();

  // ---- epilogue: z_out = free ? arccos(clip(-V.v0))/pi : z  (f64) ----
  for (int m = 0; m < 32; ++m) {
    int n = m * 32 + jg;
    if (n >= 1 && n <= NIN) {
      float zo;
      if (freeS[n] != 0) {
        double dot = red32d((double)Vs[n * KDIM + k] * v0kd);
        double ca  = fmin(fmax(-dot, -1.0 + 1e-7), 1.0 - 1e-7);
        zo = (float)(acos(ca) / PI_D);
      } else {
        zo = zin[b * NIN + n - 1];
      }
      if (k == 0) out[b * NIN + n - 1] = zo;
    }
  }
}

extern "C" void kernel_launch(void* const* d_in, const int* in_sizes, int n_in,
                              void* d_out, int out_size, void* d_ws, size_t ws_size,
                              hipStream_t stream) {
  const float* C        = (const float*)d_in[0];
  const float* z        = (const float*)d_in[1];
  const int*   is_input = (const int*)d_in[2];
  float*       out      = (float*)d_out;
  (void)d_ws; (void)ws_size;

  (void)hipFuncSetAttribute((const void*)mixnet_kernel,
                            hipFuncAttributeMaxDynamicSharedMemorySize,
                            SMEM_BYTES);

  mixnet_kernel<<<BATCH, 1024, SMEM_BYTES, stream>>>(C, z, is_input, out);
}

// Round 9
// 6512.513 us; speedup vs baseline: 5.3389x; 1.2803x over previous
//
#include <hip/hip_runtime.h>
#include <stdint.h>
#include <math.h>

#define NVARS 1024
#define KDIM 32
#define BATCH 64
#define NIN 768
#define MAXIT 10

// LDS layout (bytes):
//   Vs    @ 0       float [1024][36] (padded)  147456   (init GEMM staging only)
//   freeS @ 147456  int   [1024]                 4096
//   dvB   @ 151552  float [2][32]                 256
//   v0D   @ 151808  double[32]                    256
#define SMEM_BYTES 152064

// ---- threefry2x32 block, exactly matching JAX (20 rounds, inject every 4) ----
__device__ __forceinline__ void tf2x32(uint32_t key0, uint32_t key1,
                                       uint32_t& x0, uint32_t& x1) {
  uint32_t ks2 = key0 ^ key1 ^ 0x1BD11BDAu;
  x0 += key0; x1 += key1;
#define TFR(r) { x0 += x1; x1 = (x1 << r) | (x1 >> (32 - r)); x1 ^= x0; }
  TFR(13) TFR(15) TFR(26) TFR(6)
  x0 += key1; x1 += ks2 + 1u;
  TFR(17) TFR(29) TFR(16) TFR(24)
  x0 += ks2;  x1 += key0 + 2u;
  TFR(13) TFR(15) TFR(26) TFR(6)
  x0 += key0; x1 += key1 + 3u;
  TFR(17) TFR(29) TFR(16) TFR(24)
  x0 += key1; x1 += ks2 + 4u;
  TFR(13) TFR(15) TFR(26) TFR(6)
  x0 += ks2;  x1 += key0 + 5u;
#undef TFR
}

// partitionable random_bits (32-bit): counter (0, flat), out = x0 ^ x1
__device__ __forceinline__ uint32_t pbits(uint32_t k0, uint32_t k1, uint32_t flat) {
  uint32_t x0 = 0u, x1 = flat;
  tf2x32(k0, k1, x0, x1);
  return x0 ^ x1;
}

// ---- XLA f32 erf_inv (Giles polynomial) ----
__device__ __forceinline__ float erfinv_xla(float x) {
  float w = -log1pf(-x * x);
  float p;
  if (w < 5.0f) {
    w -= 2.5f;
    p = 2.81022636e-08f;
    p = fmaf(p, w, 3.43273939e-07f);
    p = fmaf(p, w, -3.5233877e-06f);
    p = fmaf(p, w, -4.39150654e-06f);
    p = fmaf(p, w, 0.00021858087f);
    p = fmaf(p, w, -0.00125372503f);
    p = fmaf(p, w, -0.00417768164f);
    p = fmaf(p, w, 0.246640727f);
    p = fmaf(p, w, 1.50140941f);
  } else {
    w = sqrtf(w) - 3.0f;
    p = -0.000200214257f;
    p = fmaf(p, w, 0.000100950558f);
    p = fmaf(p, w, 0.00134934322f);
    p = fmaf(p, w, -0.00367342844f);
    p = fmaf(p, w, 0.00573950773f);
    p = fmaf(p, w, -0.0076224613f);
    p = fmaf(p, w, 0.00943887047f);
    p = fmaf(p, w, 1.00167406f);
    p = fmaf(p, w, 2.83297682f);
  }
  return p * x;
}

__device__ __forceinline__ float bits_to_normal(uint32_t bits) {
  uint32_t fb = (bits >> 9) | 0x3F800000u;
  float f = __uint_as_float(fb) - 1.0f;
  const float lo = -0.99999994f;
  float u = fmaf(f, 2.0f, lo);
  u = fmaxf(lo, u);
  return 1.41421356237f * erfinv_xla(u);
}

// butterfly sum across 32-lane group (threads 0..31 usage)
__device__ __forceinline__ double red32d(double v) {
  v += __shfl_xor(v, 16);
  v += __shfl_xor(v, 8);
  v += __shfl_xor(v, 4);
  v += __shfl_xor(v, 2);
  v += __shfl_xor(v, 1);
  return v;
}

__global__ __launch_bounds__(1024, 4) void mixnet_kernel(
    const float* __restrict__ C32, const float* __restrict__ zin,
    const int* __restrict__ is_in, float* __restrict__ out) {
  extern __shared__ char smemraw[];
  float*  Vs    = (float*)smemraw;                       // [1024][36]
  int*    freeS = (int*)(smemraw + 147456);              // [1024]
  float*  dvB   = (float*)(smemraw + 151552);            // [2][32]
  double* v0D   = (double*)(smemraw + 151808);           // [32]

  const int tid = threadIdx.x;   // = variable index j
  const int b   = blockIdx.x;

  // ---- free flags ----
  {
    int fr;
    if (tid == 0) fr = 0;
    else if (tid <= NIN) fr = (is_in[b * NIN + tid - 1] == 0) ? 1 : 0;
    else fr = 1;
    freeS[tid] = fr;
  }

  // k1, k2 = jax.random.split(jax.random.key(42))  [partitionable]
  uint32_t a0 = 0u, a1 = 0u; tf2x32(0u, 42u, a0, a1);
  uint32_t b0 = 0u, b1 = 1u; tf2x32(0u, 42u, b0, b1);

  // ---- v0: threads 0..31 compute and stage to LDS (same butterfly as R8) ----
  if (tid < 32) {
    float raw = bits_to_normal(pbits(a0, a1, (uint32_t)(b * KDIM + tid)));
    double n2 = red32d((double)raw * (double)raw);
    v0D[tid] = (double)raw / sqrt(n2);
  }
  __syncthreads();

  const double PI_D = 3.14159265358979323846;

  // ---- build V row j = tid (f64 math, in-thread), store f32 regs + LDS ----
  float vr[32];
  {
    double vrow[32];
    if (tid == 0) {
#pragma unroll
      for (int t = 0; t < 16; ++t) {
        double2 w = *(const double2*)(v0D + 2 * t);
        vrow[2 * t] = w.x; vrow[2 * t + 1] = w.y;
      }
    } else {
      uint32_t base = ((uint32_t)(b * NVARS + tid)) * KDIM;
#pragma unroll
      for (int q = 0; q < 32; ++q)
        vrow[q] = (double)bits_to_normal(pbits(b0, b1, base + (uint32_t)q));
      double dot = 0.0;
#pragma unroll
      for (int t = 0; t < 16; ++t) {
        double2 w = *(const double2*)(v0D + 2 * t);
        dot += vrow[2 * t] * w.x + vrow[2 * t + 1] * w.y;
      }
#pragma unroll
      for (int t = 0; t < 16; ++t) {
        double2 w = *(const double2*)(v0D + 2 * t);
        vrow[2 * t]     -= dot * w.x;
        vrow[2 * t + 1] -= dot * w.y;
      }
      double n2 = 0.0;
#pragma unroll
      for (int q = 0; q < 32; ++q) n2 += vrow[q] * vrow[q];
      double rinv = 1.0 / sqrt(n2);
#pragma unroll
      for (int q = 0; q < 32; ++q) vrow[q] *= rinv;
      if (tid <= NIN && is_in[b * NIN + tid - 1] > 0) {
        double zf = (double)zin[b * NIN + tid - 1];
        double cc = cos(PI_D * zf), sn = sin(PI_D * zf);
#pragma unroll
        for (int t = 0; t < 16; ++t) {
          double2 w = *(const double2*)(v0D + 2 * t);
          vrow[2 * t]     = -cc * w.x + sn * vrow[2 * t];
          vrow[2 * t + 1] = -cc * w.y + sn * vrow[2 * t + 1];
        }
      }
    }
#pragma unroll
    for (int q = 0; q < 32; ++q) vr[q] = (float)vrow[q];
  }
  // stage V to LDS (padded rows; one-time 4-way bank aliasing is fine)
#pragma unroll
  for (int q = 0; q < 8; ++q) {
    float4 w; w.x = vr[4 * q]; w.y = vr[4 * q + 1];
    w.z = vr[4 * q + 2]; w.w = vr[4 * q + 3];
    *(float4*)(Vs + tid * 36 + 4 * q) = w;
  }
  __syncthreads();

  // ---- init G[j][k] = sum_i C[j][i] * V[i][k]  (f32, ascending i) ----
  float Gj[32];
#pragma unroll
  for (int q = 0; q < 32; ++q) Gj[q] = 0.f;
  {
    const float* crow = C32 + (size_t)tid * NVARS;
    for (int i = 0; i < NVARS; i += 4) {
      float4 c4 = *(const float4*)(crow + i);
#pragma unroll
      for (int u = 0; u < 4; ++u) {
        float cu = (u == 0) ? c4.x : (u == 1) ? c4.y : (u == 2) ? c4.z : c4.w;
        const float4* vp = (const float4*)(Vs + (i + u) * 36);
#pragma unroll
        for (int q = 0; q < 8; ++q) {
          float4 v = vp[q];
          Gj[4 * q]     = fmaf(cu, v.x, Gj[4 * q]);
          Gj[4 * q + 1] = fmaf(cu, v.y, Gj[4 * q + 1]);
          Gj[4 * q + 2] = fmaf(cu, v.z, Gj[4 * q + 2]);
          Gj[4 * q + 3] = fmaf(cu, v.w, Gj[4 * q + 3]);
        }
      }
    }
  }
  __syncthreads();

  // ---- solve: 10 sweeps, maintained-G coordinate descent ----
  // Owner = thread i (holds G[i][:] and V[i][:] in regs). dv via LDS broadcast.
  int p = 0;
  for (int it = 0; it < MAXIT; ++it) {
    for (int i = 1; i < NVARS; ++i) {
      if (freeS[i] == 0) continue;          // block-uniform skip

      float cme = C32[(size_t)i * NVARS + tid];  // coalesced; prefetched early

      if (tid == i) {                       // in-thread norm + dv
        float s0 = 0.f, s1 = 0.f, s2 = 0.f, s3 = 0.f;
#pragma unroll
        for (int q = 0; q < 8; ++q) {
          s0 = fmaf(Gj[4 * q],     Gj[4 * q],     s0);
          s1 = fmaf(Gj[4 * q + 1], Gj[4 * q + 1], s1);
          s2 = fmaf(Gj[4 * q + 2], Gj[4 * q + 2], s2);
          s3 = fmaf(Gj[4 * q + 3], Gj[4 * q + 3], s3);
        }
        float gn  = fmaxf(sqrtf((s0 + s1) + (s2 + s3)), 1e-12f);
        float inv = -1.0f / gn;
        float4* dvp = (float4*)(dvB + p * 32);
#pragma unroll
        for (int q = 0; q < 8; ++q) {
          float4 d;
          float v0n = Gj[4 * q] * inv;     d.x = v0n - vr[4 * q];     vr[4 * q] = v0n;
          float v1n = Gj[4 * q + 1] * inv; d.y = v1n - vr[4 * q + 1]; vr[4 * q + 1] = v1n;
          float v2n = Gj[4 * q + 2] * inv; d.z = v2n - vr[4 * q + 2]; vr[4 * q + 2] = v2n;
          float v3n = Gj[4 * q + 3] * inv; d.w = v3n - vr[4 * q + 3]; vr[4 * q + 3] = v3n;
          dvp[q] = d;
        }
      }
      __syncthreads();
      const float4* dvp = (const float4*)(dvB + p * 32);
#pragma unroll
      for (int q = 0; q < 8; ++q) {
        float4 d = dvp[q];                  // same-address broadcast read
        Gj[4 * q]     = fmaf(cme, d.x, Gj[4 * q]);
        Gj[4 * q + 1] = fmaf(cme, d.y, Gj[4 * q + 1]);
        Gj[4 * q + 2] = fmaf(cme, d.z, Gj[4 * q + 2]);
        Gj[4 * q + 3] = fmaf(cme, d.w, Gj[4 * q + 3]);
      }
      p ^= 1;
    }
  }

  // ---- epilogue: z_out = free ? arccos(clip(-V.v0))/pi : z  (f64 in-thread) ----
  if (tid >= 1 && tid <= NIN) {
    float zo;
    if (freeS[tid] != 0) {
      double dot = 0.0;
#pragma unroll
      for (int t = 0; t < 16; ++t) {
        double2 w = *(const double2*)(v0D + 2 * t);
        dot += (double)vr[2 * t] * w.x + (double)vr[2 * t + 1] * w.y;
      }
      double ca = fmin(fmax(-dot, -1.0 + 1e-7), 1.0 - 1e-7);
      zo = (float)(acos(ca) / PI_D);
    } else {
      zo = zin[b * NIN + tid - 1];
    }
    out[b * NIN + tid - 1] = zo;
  }
}

extern "C" void kernel_launch(void* const* d_in, const int* in_sizes, int n_in,
                              void* d_out, int out_size, void* d_ws, size_t ws_size,
                              hipStream_t stream) {
  const float* C        = (const float*)d_in[0];
  const float* z        = (const float*)d_in[1];
  const int*   is_input = (const int*)d_in[2];
  float*       out      = (float*)d_out;
  (void)d_ws; (void)ws_size;

  (void)hipFuncSetAttribute((const void*)mixnet_kernel,
                            hipFuncAttributeMaxDynamicSharedMemorySize,
                            SMEM_BYTES);

  mixnet_kernel<<<BATCH, 1024, SMEM_BYTES, stream>>>(C, z, is_input, out);
}

// Round 10
// 4717.903 us; speedup vs baseline: 7.3697x; 1.3804x over previous
//
#include <hip/hip_runtime.h>
#include <stdint.h>
#include <math.h>

#define NVARS 1024
#define KDIM 32
#define BATCH 64
#define NIN 768
#define MAXIT 10

// LDS layout (bytes):
//   Vs    @ 0       float [1024][36] (padded rows)  147456  (V state, whole kernel)
//   fmask @ 147456  uint  [32]                         128  (free bits, 32 rows/word)
//   dvB   @ 147584  float [2][32]                      256
//   v0D   @ 147840  double[32]                         256
#define SMEM_BYTES 148096

// ---- threefry2x32 block, exactly matching JAX (20 rounds, inject every 4) ----
__device__ __forceinline__ void tf2x32(uint32_t key0, uint32_t key1,
                                       uint32_t& x0, uint32_t& x1) {
  uint32_t ks2 = key0 ^ key1 ^ 0x1BD11BDAu;
  x0 += key0; x1 += key1;
#define TFR(r) { x0 += x1; x1 = (x1 << r) | (x1 >> (32 - r)); x1 ^= x0; }
  TFR(13) TFR(15) TFR(26) TFR(6)
  x0 += key1; x1 += ks2 + 1u;
  TFR(17) TFR(29) TFR(16) TFR(24)
  x0 += ks2;  x1 += key0 + 2u;
  TFR(13) TFR(15) TFR(26) TFR(6)
  x0 += key0; x1 += key1 + 3u;
  TFR(17) TFR(29) TFR(16) TFR(24)
  x0 += key1; x1 += ks2 + 4u;
  TFR(13) TFR(15) TFR(26) TFR(6)
  x0 += ks2;  x1 += key0 + 5u;
#undef TFR
}

// partitionable random_bits (32-bit): counter (0, flat), out = x0 ^ x1
__device__ __forceinline__ uint32_t pbits(uint32_t k0, uint32_t k1, uint32_t flat) {
  uint32_t x0 = 0u, x1 = flat;
  tf2x32(k0, k1, x0, x1);
  return x0 ^ x1;
}

// ---- XLA f32 erf_inv (Giles polynomial) ----
__device__ __forceinline__ float erfinv_xla(float x) {
  float w = -log1pf(-x * x);
  float p;
  if (w < 5.0f) {
    w -= 2.5f;
    p = 2.81022636e-08f;
    p = fmaf(p, w, 3.43273939e-07f);
    p = fmaf(p, w, -3.5233877e-06f);
    p = fmaf(p, w, -4.39150654e-06f);
    p = fmaf(p, w, 0.00021858087f);
    p = fmaf(p, w, -0.00125372503f);
    p = fmaf(p, w, -0.00417768164f);
    p = fmaf(p, w, 0.246640727f);
    p = fmaf(p, w, 1.50140941f);
  } else {
    w = sqrtf(w) - 3.0f;
    p = -0.000200214257f;
    p = fmaf(p, w, 0.000100950558f);
    p = fmaf(p, w, 0.00134934322f);
    p = fmaf(p, w, -0.00367342844f);
    p = fmaf(p, w, 0.00573950773f);
    p = fmaf(p, w, -0.0076224613f);
    p = fmaf(p, w, 0.00943887047f);
    p = fmaf(p, w, 1.00167406f);
    p = fmaf(p, w, 2.83297682f);
  }
  return p * x;
}

__device__ __forceinline__ float bits_to_normal(uint32_t bits) {
  uint32_t fb = (bits >> 9) | 0x3F800000u;
  float f = __uint_as_float(fb) - 1.0f;
  const float lo = -0.99999994f;
  float u = fmaf(f, 2.0f, lo);
  u = fmaxf(lo, u);
  return 1.41421356237f * erfinv_xla(u);
}

__device__ __forceinline__ double red32d(double v) {
  v += __shfl_xor(v, 16);
  v += __shfl_xor(v, 8);
  v += __shfl_xor(v, 4);
  v += __shfl_xor(v, 2);
  v += __shfl_xor(v, 1);
  return v;
}

__global__ __launch_bounds__(1024, 4) void mixnet_kernel(
    const float* __restrict__ C32, const float* __restrict__ zin,
    const int* __restrict__ is_in, float* __restrict__ out) {
  extern __shared__ char smemraw[];
  float*    Vs    = (float*)smemraw;                     // [1024][36]
  uint32_t* fmask = (uint32_t*)(smemraw + 147456);       // [32]
  float*    dvB   = (float*)(smemraw + 147584);          // [2][32]
  double*   v0D   = (double*)(smemraw + 147840);         // [32]

  const int tid  = threadIdx.x;
  const int b    = blockIdx.x;
  const int jg   = tid >> 3;   // 0..127: owns G rows 8jg..8jg+7
  const int kg   = tid & 7;    // 0..7:  owns k 4kg..4kg+3
  const int lane = tid & 63;
  const int wave = tid >> 6;

  // ---- free bits -> fmask words (32 rows per word) ----
  {
    int row = tid;
    bool fr;
    if (row == 0) fr = false;
    else if (row <= NIN) fr = (is_in[b * NIN + row - 1] == 0);
    else fr = true;
    unsigned long long m = __ballot(fr);
    if (lane == 0) {
      fmask[2 * wave]     = (uint32_t)m;
      fmask[2 * wave + 1] = (uint32_t)(m >> 32);
    }
  }

  // k1, k2 = jax.random.split(jax.random.key(42))  [partitionable]
  uint32_t a0 = 0u, a1 = 0u; tf2x32(0u, 42u, a0, a1);
  uint32_t b0 = 0u, b1 = 1u; tf2x32(0u, 42u, b0, b1);

  // ---- v0: threads 0..31 (butterfly, bitwise same as R9) ----
  if (tid < 32) {
    float raw = bits_to_normal(pbits(a0, a1, (uint32_t)(b * KDIM + tid)));
    double n2 = red32d((double)raw * (double)raw);
    v0D[tid] = (double)raw / sqrt(n2);
  }
  __syncthreads();

  const double PI_D = 3.14159265358979323846;

  // ---- build V row j = tid (f64 in-thread, bitwise same as R9), stage Vs ----
  {
    double vrow[32];
    if (tid == 0) {
#pragma unroll
      for (int t = 0; t < 16; ++t) {
        double2 w = *(const double2*)(v0D + 2 * t);
        vrow[2 * t] = w.x; vrow[2 * t + 1] = w.y;
      }
    } else {
      uint32_t base = ((uint32_t)(b * NVARS + tid)) * KDIM;
#pragma unroll
      for (int q = 0; q < 32; ++q)
        vrow[q] = (double)bits_to_normal(pbits(b0, b1, base + (uint32_t)q));
      double dot = 0.0;
#pragma unroll
      for (int t = 0; t < 16; ++t) {
        double2 w = *(const double2*)(v0D + 2 * t);
        dot += vrow[2 * t] * w.x + vrow[2 * t + 1] * w.y;
      }
#pragma unroll
      for (int t = 0; t < 16; ++t) {
        double2 w = *(const double2*)(v0D + 2 * t);
        vrow[2 * t]     -= dot * w.x;
        vrow[2 * t + 1] -= dot * w.y;
      }
      double n2 = 0.0;
#pragma unroll
      for (int q = 0; q < 32; ++q) n2 += vrow[q] * vrow[q];
      double rinv = 1.0 / sqrt(n2);
#pragma unroll
      for (int q = 0; q < 32; ++q) vrow[q] *= rinv;
      if (tid <= NIN && is_in[b * NIN + tid - 1] > 0) {
        double zf = (double)zin[b * NIN + tid - 1];
        double cc = cos(PI_D * zf), sn = sin(PI_D * zf);
#pragma unroll
        for (int t = 0; t < 16; ++t) {
          double2 w = *(const double2*)(v0D + 2 * t);
          vrow[2 * t]     = -cc * w.x + sn * vrow[2 * t];
          vrow[2 * t + 1] = -cc * w.y + sn * vrow[2 * t + 1];
        }
      }
    }
#pragma unroll
    for (int q = 0; q < 8; ++q) {
      float4 w;
      w.x = (float)vrow[4 * q];     w.y = (float)vrow[4 * q + 1];
      w.z = (float)vrow[4 * q + 2]; w.w = (float)vrow[4 * q + 3];
      *(float4*)(Vs + tid * 36 + 4 * q) = w;
    }
  }
  __syncthreads();

  // ---- init G in 2-D layout: Gj[l*4+m] = G[8jg+l][4kg+m], ascending i ----
  float Gj[32];
#pragma unroll
  for (int q = 0; q < 32; ++q) Gj[q] = 0.f;
  {
    const float* Cb = C32 + (size_t)(8 * jg) * NVARS;
    for (int i = 0; i < NVARS; i += 4) {
      float4 cw[8];
#pragma unroll
      for (int l = 0; l < 8; ++l)
        cw[l] = *(const float4*)(Cb + (size_t)l * NVARS + i);
#pragma unroll
      for (int u = 0; u < 4; ++u) {
        float4 vv = *(const float4*)(Vs + (i + u) * 36 + 4 * kg);
#pragma unroll
        for (int l = 0; l < 8; ++l) {
          float cu = (u == 0) ? cw[l].x : (u == 1) ? cw[l].y
                   : (u == 2) ? cw[l].z : cw[l].w;
          Gj[l * 4 + 0] = fmaf(cu, vv.x, Gj[l * 4 + 0]);
          Gj[l * 4 + 1] = fmaf(cu, vv.y, Gj[l * 4 + 1]);
          Gj[l * 4 + 2] = fmaf(cu, vv.z, Gj[l * 4 + 2]);
          Gj[l * 4 + 3] = fmaf(cu, vv.w, Gj[l * 4 + 3]);
        }
      }
    }
  }
  __syncthreads();

  // ---- solve: 10 sweeps, maintained-G coordinate descent, 2-D ownership ----
  int p = 0;
  for (int it = 0; it < MAXIT; ++it) {
    for (int grp = 0; grp < 32; ++grp) {
      const uint32_t fm = fmask[grp];          // uniform
      if (fm == 0u) continue;
      const float* Cg = C32 + (size_t)(grp * 32) * NVARS + 8 * jg;
#pragma unroll
      for (int ii = 0; ii < 32; ++ii) {
        if (!((fm >> ii) & 1u)) continue;      // uniform branch
        const int i = grp * 32 + ii;
        const float* crow = Cg + (size_t)ii * NVARS;
        float4 cpa = *(const float4*)crow;       // C[i][8jg..8jg+3]
        float4 cpb = *(const float4*)(crow + 4); // C[i][8jg+4..8jg+7]

        if (jg == 4 * grp + (ii >> 3)) {       // owner: 8 lanes of one wave
          const int l = ii & 7;                // compile-time (unrolled)
          float s = Gj[l * 4 + 0] * Gj[l * 4 + 0];
          s = fmaf(Gj[l * 4 + 1], Gj[l * 4 + 1], s);
          s = fmaf(Gj[l * 4 + 2], Gj[l * 4 + 2], s);
          s = fmaf(Gj[l * 4 + 3], Gj[l * 4 + 3], s);
          s += __shfl_xor(s, 1);
          s += __shfl_xor(s, 2);
          s += __shfl_xor(s, 4);
          float gn  = fmaxf(sqrtf(s), 1e-12f);
          float inv = -1.0f / gn;
          float4 vold = *(const float4*)(Vs + i * 36 + 4 * kg);
          float4 vnew, d;
          vnew.x = Gj[l * 4 + 0] * inv; d.x = vnew.x - vold.x;
          vnew.y = Gj[l * 4 + 1] * inv; d.y = vnew.y - vold.y;
          vnew.z = Gj[l * 4 + 2] * inv; d.z = vnew.z - vold.z;
          vnew.w = Gj[l * 4 + 3] * inv; d.w = vnew.w - vold.w;
          *(float4*)(Vs + i * 36 + 4 * kg) = vnew;
          *(float4*)(dvB + p * 32 + 4 * kg) = d;
        }
        __syncthreads();
        const float4 d = *(const float4*)(dvB + p * 32 + 4 * kg);
#pragma unroll
        for (int l2 = 0; l2 < 8; ++l2) {
          float c = (l2 == 0) ? cpa.x : (l2 == 1) ? cpa.y : (l2 == 2) ? cpa.z
                  : (l2 == 3) ? cpa.w : (l2 == 4) ? cpb.x : (l2 == 5) ? cpb.y
                  : (l2 == 6) ? cpb.z : cpb.w;
          Gj[l2 * 4 + 0] = fmaf(c, d.x, Gj[l2 * 4 + 0]);
          Gj[l2 * 4 + 1] = fmaf(c, d.y, Gj[l2 * 4 + 1]);
          Gj[l2 * 4 + 2] = fmaf(c, d.z, Gj[l2 * 4 + 2]);
          Gj[l2 * 4 + 3] = fmaf(c, d.w, Gj[l2 * 4 + 3]);
        }
        p ^= 1;
      }
    }
  }
  __syncthreads();

  // ---- epilogue: thread=j, V from Vs, f64 ----
  if (tid >= 1 && tid <= NIN) {
    bool fr = (fmask[tid >> 5] >> (tid & 31)) & 1u;
    float zo;
    if (fr) {
      double dot = 0.0;
#pragma unroll
      for (int t = 0; t < 16; ++t) {
        double2 w = *(const double2*)(v0D + 2 * t);
        dot += (double)Vs[tid * 36 + 2 * t] * w.x
             + (double)Vs[tid * 36 + 2 * t + 1] * w.y;
      }
      double ca = fmin(fmax(-dot, -1.0 + 1e-7), 1.0 - 1e-7);
      zo = (float)(acos(ca) / PI_D);
    } else {
      zo = zin[b * NIN + tid - 1];
    }
    out[b * NIN + tid - 1] = zo;
  }
}

extern "C" void kernel_launch(void* const* d_in, const int* in_sizes, int n_in,
                              void* d_out, int out_size, void* d_ws, size_t ws_size,
                              hipStream_t stream) {
  const float* C        = (const float*)d_in[0];
  const float* z        = (const float*)d_in[1];
  const int*   is_input = (const int*)d_in[2];
  float*       out      = (float*)d_out;
  (void)d_ws; (void)ws_size;

  (void)hipFuncSetAttribute((const void*)mixnet_kernel,
                            hipFuncAttributeMaxDynamicSharedMemorySize,
                            SMEM_BYTES);

  mixnet_kernel<<<BATCH, 1024, SMEM_BYTES, stream>>>(C, z, is_input, out);
}